// Round 4
// baseline (854.528 us; speedup 1.0000x reference)
//
#include <hip/hip_runtime.h>

// LGA (GANet Local Guided Aggregation), radius=2, K=5.
// in1: [N=4, C=32, H=384, W=768] f32
// in2: [N=4, 25,   H=384, W=768] f32 (per-pixel 5x5 taps, shared across C)
// out: [N, C, H, W] f32
//
// v3b (second resubmit): rounds 2-3 failed with "container failed twice" —
// no compile error / absmax / counters, and round-1 timing already showed a
// degraded harness (push_in_npz_s=1082s). Kernel OOB/alignment/launch audit
// is clean (max indices land exactly on last elements; float2 loads 8B
// aligned; zero sync points). One defensive tweak vs v3: asm pins restored
// to `asm volatile` (the exact form that compiled+ran in v2).
//
// Design: LDS-free. v2 was 85% stall: __syncthreads drains vmcnt(0) every
// channel (32x/block), re-exposing full load latency; LDS b128 path added
// 2e7 conflict cycles; 100 weight VGPRs -> AGPR parking -> 2 waves/SIMD.
// Fix: fold ALL zero-padding into the pinned weights once (zero a component
// iff its (pixel,tap) touches an OOB row/col), then read each 8-float window
// row directly from global with CLAMPED addresses (clamped garbage only ever
// multiplies an exact-0 weight). No LDS, no barriers, fully decoupled waves;
// latency hidden by TLP. Horizontal overlap -> L1; vertical halo -> L2 with
// XCD-bijective block swizzle for y-locality.

#define N_DIM 4
#define C_DIM 32
#define H_DIM 384
#define W_DIM 768
#define HW (H_DIM * W_DIM)
#define TH 4          // output rows per block (4 waves)
#define TW 256        // output cols per block (64 lanes x 4 pixels)
#define NWG (W_DIM / TW * (H_DIM / TH) * N_DIM)   // 3*96*4 = 1152

__global__ __launch_bounds__(256, 3)
void lga_kernel(const float* __restrict__ in1,
                const float* __restrict__ in2,
                float* __restrict__ out) {
    // XCD-bijective swizzle (NWG % 8 == 0): each XCD gets 144 consecutive
    // tiles -> vertically adjacent tiles share halo rows in the same L2.
    int wg = blockIdx.x;
    wg = (wg & 7) * (NWG / 8) + (wg >> 3);
    const int bx = wg % 3;              // tile col
    const int by = (wg / 3) % (H_DIM / TH);
    const int n  = wg / (3 * (H_DIM / TH));

    const int tid = threadIdx.x;
    const int tx  = tid & 63;           // lane
    const int ty  = tid >> 6;           // wave = output row in tile
    const int h   = by * TH + ty;       // output row
    const int wb  = bx * TW + 4 * tx;   // first of 4 output cols

    // ---- 25 taps: load, fold zero-padding into them, pin in registers ----
    // out[p] tap (i,j) reads in1[row h+i-2, col p+j-2]; component e of wt[5i+j]
    // belongs to pixel wb+e -> zero it iff that row/col is OOB. After this,
    // any clamped (wrong-position) load is multiplied by an exact 0.
    float4 wt[25];
    {
        const float* w_src = in2 + ((size_t)n * 25) * HW + (size_t)h * W_DIM + wb;
#pragma unroll
        for (int i = 0; i < 5; ++i) {
            const bool rv = (unsigned)(h + i - 2) < H_DIM;
#pragma unroll
            for (int j = 0; j < 5; ++j) {
                const int t = 5 * i + j;
                float4 v = *(const float4*)(w_src + (size_t)t * HW);
                v.x = (rv && (unsigned)(wb + 0 + j - 2) < W_DIM) ? v.x : 0.f;
                v.y = (rv && (unsigned)(wb + 1 + j - 2) < W_DIM) ? v.y : 0.f;
                v.z = (rv && (unsigned)(wb + 2 + j - 2) < W_DIM) ? v.z : 0.f;
                v.w = (rv && (unsigned)(wb + 3 + j - 2) < W_DIM) ? v.w : 0.f;
                asm volatile("" : "+v"(v.x), "+v"(v.y), "+v"(v.z), "+v"(v.w));
                wt[t] = v;
            }
        }
    }

    // ---- loop-invariant clamped addresses ----
    // Window per row: cols [wb-2, wb+6). Split: b64 at o0=[wb-2,wb-1],
    // b128 at wb (16B aligned), b64 at o3=[wb+4,wb+5]. o0/o3 clamps only
    // fire when BOTH their elements are OOB -> garbage is weight-masked.
    int rowoff[5];
#pragma unroll
    for (int i = 0; i < 5; ++i) {
        int gh = h + i - 2;
        gh = gh < 0 ? 0 : (gh > H_DIM - 1 ? H_DIM - 1 : gh);
        rowoff[i] = gh * W_DIM;
    }
    const int o0 = (wb == 0) ? 0 : (wb - 2);
    const int o3 = (wb + 4 > W_DIM - 2) ? (W_DIM - 2) : (wb + 4);

    const float* src = in1 + (size_t)n * C_DIM * HW;
    float*       dst = out + (size_t)n * C_DIM * HW + (size_t)h * W_DIM + wb;

#pragma unroll 1
    for (int c = 0; c < C_DIM; ++c) {
        const float* p = src + (size_t)c * HW;

        float acc0 = 0.f, acc1 = 0.f, acc2 = 0.f, acc3 = 0.f;
#pragma unroll
        for (int i = 0; i < 5; ++i) {
            const float* pr = p + rowoff[i];
            const float2 a0 = *(const float2*)(pr + o0);   // win[0..1]
            const float4 m  = *(const float4*)(pr + wb);   // win[2..5], 16B aligned
            const float2 b1 = *(const float2*)(pr + o3);   // win[6..7]
            const float win[8] = {a0.x, a0.y, m.x, m.y, m.z, m.w, b1.x, b1.y};
#pragma unroll
            for (int j = 0; j < 5; ++j) {
                const float4 wv = wt[5 * i + j];
                acc0 += wv.x * win[j + 0];
                acc1 += wv.y * win[j + 1];
                acc2 += wv.z * win[j + 2];
                acc3 += wv.w * win[j + 3];
            }
        }

        *(float4*)(dst + (size_t)c * HW) = make_float4(acc0, acc1, acc2, acc3);
    }
}

extern "C" void kernel_launch(void* const* d_in, const int* in_sizes, int n_in,
                              void* d_out, int out_size, void* d_ws, size_t ws_size,
                              hipStream_t stream) {
    const float* in1 = (const float*)d_in[0];
    const float* in2 = (const float*)d_in[1];
    float* out = (float*)d_out;
    lga_kernel<<<dim3(NWG), 256, 0, stream>>>(in1, in2, out);
}